// Round 2
// baseline (557.588 us; speedup 1.0000x reference)
//
#include <hip/hip_runtime.h>
#include <hip/hip_bf16.h>
#include <math.h>

#define B_BATCH 8
#define SEQ 2048
#define DIM 768
#define E3 2304   // 3*DIM

typedef __bf16 bf16x8 __attribute__((ext_vector_type(8)));
typedef float floatx4 __attribute__((ext_vector_type(4)));

__device__ __forceinline__ void load_lds_16B(const __hip_bfloat16* g, __hip_bfloat16* l) {
    __builtin_amdgcn_global_load_lds((const __attribute__((address_space(1))) void*)g,
                                     (__attribute__((address_space(3))) void*)l, 16, 0, 0);
}

template<typename T> __device__ __forceinline__ T to_out(float v);
template<> __device__ __forceinline__ float to_out<float>(float v) { return v; }
template<> __device__ __forceinline__ __hip_bfloat16 to_out<__hip_bfloat16>(float v) { return __float2bfloat16(v); }

// fp32 -> bf16 conversion, 8 elements per thread (n must be a multiple of 8)
__global__ __launch_bounds__(256, 4)
void cvt_f32_bf16(const float* __restrict__ in, __hip_bfloat16* __restrict__ out, long n8)
{
    const long i = (long)blockIdx.x * blockDim.x + threadIdx.x;
    if (i >= n8) return;
    const float4* p = (const float4*)in + i * 2;
    const float4 a = p[0], b = p[1];
    union { uint4 u; __hip_bfloat16 h[8]; } t;
    t.h[0] = __float2bfloat16(a.x); t.h[1] = __float2bfloat16(a.y);
    t.h[2] = __float2bfloat16(a.z); t.h[3] = __float2bfloat16(a.w);
    t.h[4] = __float2bfloat16(b.x); t.h[5] = __float2bfloat16(b.y);
    t.h[6] = __float2bfloat16(b.z); t.h[7] = __float2bfloat16(b.w);
    ((uint4*)out)[i] = t.u;
}

// C[M x N] = scale * (A [M x K] * B^T or B) + bias
// TRANSB=true : Bm is [N x K] row-major (weights / K^T), B^T-form GEMM
// TRANSB=false: Bm is [K x N] row-major (V), staged transposed into LDS
template<bool TRANSB, typename OutT>
__global__ __launch_bounds__(256, 2)
void gemm128(const __hip_bfloat16* __restrict__ A, long lda, long sA,
             const __hip_bfloat16* __restrict__ Bm, long ldb, long sB,
             OutT* __restrict__ C, long ldc, long sC,
             const float* __restrict__ bias, float scale, int K)
{
    __shared__ __hip_bfloat16 As[128 * 32];
    __shared__ __hip_bfloat16 Bs[128 * 32];   // always [n][k] layout for frag reads

    A  += (long)blockIdx.z * sA;
    Bm += (long)blockIdx.z * sB;
    C  += (long)blockIdx.z * sC;

    const int n0   = blockIdx.x * 128;
    const int m0   = blockIdx.y * 128;
    const int tid  = threadIdx.x;
    const int wave = tid >> 6;
    const int lane = tid & 63;
    const int wm   = (wave & 1) * 64;
    const int wn   = (wave >> 1) * 64;

    // global_load_lds: HW writes LDS at (uniform base) + lane*16B.
    // lane -> row chunk*16 + (lane>>2), elem col (lane&3)*8
    const int sr = lane >> 2;
    const int sc = (lane & 3) * 8;

    // MFMA A/B fragment: m(or n)=lane&15, k=(lane>>4)*8 + j  [verified m89/m91]
    const int fr = lane & 15;
    const int fk = (lane >> 4) * 8;

    floatx4 acc[4][4] = {};

    for (int k0 = 0; k0 < K; k0 += 32) {
#pragma unroll
        for (int c = 0; c < 2; ++c) {
            const int chunk = wave * 2 + c;            // wave-uniform
            const int row   = chunk * 16 + sr;
            load_lds_16B(A + (long)(m0 + row) * lda + (k0 + sc), As + chunk * 512);
            if (TRANSB) {
                load_lds_16B(Bm + (long)(n0 + row) * ldb + (k0 + sc), Bs + chunk * 512);
            }
        }
        if (!TRANSB) {
            // stage V-tile transposed: Bs[n][k] = Bm[k0+k][n0+n]
#pragma unroll
            for (int c = 0; c < 2; ++c) {
                const int seg = c * 256 + tid;         // 0..511 16B segments
                const int kk  = seg >> 4;              // 0..31
                const int cb  = (seg & 15) * 8;        // n col base
                union { uint4 u; __hip_bfloat16 h[8]; } t;
                t.u = *(const uint4*)(Bm + (long)(k0 + kk) * ldb + (n0 + cb));
#pragma unroll
                for (int j = 0; j < 8; ++j)
                    Bs[(cb + j) * 32 + kk] = t.h[j];
            }
        }
        __syncthreads();

        bf16x8 af[4], bfr[4];
#pragma unroll
        for (int i = 0; i < 4; ++i) {
            af[i]  = *(const bf16x8*)(As + (wm + i * 16 + fr) * 32 + fk);
            bfr[i] = *(const bf16x8*)(Bs + (wn + i * 16 + fr) * 32 + fk);
        }
#pragma unroll
        for (int mi = 0; mi < 4; ++mi)
#pragma unroll
            for (int ni = 0; ni < 4; ++ni)
                acc[mi][ni] = __builtin_amdgcn_mfma_f32_16x16x32_bf16(
                    af[mi], bfr[ni], acc[mi][ni], 0, 0, 0);
        __syncthreads();
    }

    // C/D layout: col = lane&15, row = (lane>>4)*4 + reg  [verified m89/m91]
    const int cr = (lane >> 4) * 4;
    const int cc = lane & 15;
#pragma unroll
    for (int ni = 0; ni < 4; ++ni) {
        const int col = n0 + wn + ni * 16 + cc;
        const float bv = bias ? bias[col] : 0.0f;
#pragma unroll
        for (int mi = 0; mi < 4; ++mi) {
#pragma unroll
            for (int r = 0; r < 4; ++r) {
                const int row = m0 + wm + mi * 16 + cr + r;
                C[(long)row * ldc + col] = to_out<OutT>(acc[mi][ni][r] * scale + bv);
            }
        }
    }
}

// in-place softmax over rows of length SEQ (bf16), one block per row
__global__ __launch_bounds__(256, 4)
void softmax_rows(__hip_bfloat16* __restrict__ S, long sB)
{
    __hip_bfloat16* row = S + (long)blockIdx.z * sB + (long)blockIdx.x * SEQ;
    const int tid  = threadIdx.x;
    const int wave = tid >> 6;
    const int lane = tid & 63;

    union { uint4 u; __hip_bfloat16 h[8]; } t;
    t.u = *(const uint4*)(row + tid * 8);
    float v[8];
#pragma unroll
    for (int j = 0; j < 8; ++j) v[j] = __bfloat162float(t.h[j]);

    float mx = v[0];
#pragma unroll
    for (int j = 1; j < 8; ++j) mx = fmaxf(mx, v[j]);
    for (int off = 32; off > 0; off >>= 1) mx = fmaxf(mx, __shfl_xor(mx, off, 64));

    __shared__ float redm[4], reds[4];
    if (lane == 0) redm[wave] = mx;
    __syncthreads();
    mx = fmaxf(fmaxf(redm[0], redm[1]), fmaxf(redm[2], redm[3]));

    float e[8], s = 0.f;
#pragma unroll
    for (int j = 0; j < 8; ++j) { e[j] = __expf(v[j] - mx); s += e[j]; }
    for (int off = 32; off > 0; off >>= 1) s += __shfl_xor(s, off, 64);
    if (lane == 0) reds[wave] = s;
    __syncthreads();
    s = reds[0] + reds[1] + reds[2] + reds[3];
    const float inv = 1.f / s;

#pragma unroll
    for (int j = 0; j < 8; ++j) t.h[j] = __float2bfloat16(e[j] * inv);
    *(uint4*)(row + tid * 8) = t.u;
}

extern "C" void kernel_launch(void* const* d_in, const int* in_sizes, int n_in,
                              void* d_out, int out_size, void* d_ws, size_t ws_size,
                              hipStream_t stream)
{
    const float* x     = (const float*)d_in[0];
    const float* w_qkv = (const float*)d_in[1];
    const float* b_qkv = (const float*)d_in[2];
    const float* w_prj = (const float*)d_in[3];
    const float* b_prj = (const float*)d_in[4];
    float* out = (float*)d_out;

    const float alpha = 1.0f / (sqrtf((float)DIM) * 3.0f);  // qk scale / temperature

    const size_t XE  = (size_t)B_BATCH * SEQ * DIM;   // 12.58M
    const size_t WQE = (size_t)E3 * DIM;              // 1.77M
    const size_t WPE = (size_t)DIM * DIM;             // 0.59M
    const size_t QKVE = (size_t)B_BATCH * SEQ * E3;   // 37.75M
    const size_t SE   = (size_t)B_BATCH * SEQ * SEQ;  // 33.55M
    const size_t OE   = XE;
    dim3 blk(256);

    const size_t full_bytes = (XE + WQE + WPE + QKVE + SE + OE) * sizeof(__hip_bfloat16);

    if (ws_size >= full_bytes) {
        __hip_bfloat16* xb  = (__hip_bfloat16*)d_ws;
        __hip_bfloat16* wqb = xb + XE;
        __hip_bfloat16* wpb = wqb + WQE;
        __hip_bfloat16* qkv = wpb + WPE;
        __hip_bfloat16* S   = qkv + QKVE;
        __hip_bfloat16* O   = S + SE;

        cvt_f32_bf16<<<dim3((XE / 8 + 255) / 256), blk, 0, stream>>>(x, xb, XE / 8);
        cvt_f32_bf16<<<dim3((WQE / 8 + 255) / 256), blk, 0, stream>>>(w_qkv, wqb, WQE / 8);
        cvt_f32_bf16<<<dim3((WPE / 8 + 255) / 256), blk, 0, stream>>>(w_prj, wpb, WPE / 8);

        gemm128<true, __hip_bfloat16><<<dim3(E3 / 128, (B_BATCH * SEQ) / 128, 1), blk, 0, stream>>>(
            xb, DIM, 0, wqb, DIM, 0, qkv, E3, 0, b_qkv, 1.0f, DIM);
        gemm128<true, __hip_bfloat16><<<dim3(SEQ / 128, SEQ / 128, B_BATCH), blk, 0, stream>>>(
            qkv, E3, (long)SEQ * E3, qkv + DIM, E3, (long)SEQ * E3,
            S, SEQ, (long)SEQ * SEQ, nullptr, alpha, DIM);
        softmax_rows<<<dim3(SEQ, 1, B_BATCH), blk, 0, stream>>>(S, (long)SEQ * SEQ);
        gemm128<false, __hip_bfloat16><<<dim3(DIM / 128, SEQ / 128, B_BATCH), blk, 0, stream>>>(
            S, SEQ, (long)SEQ * SEQ, qkv + 2 * DIM, E3, (long)SEQ * E3,
            O, DIM, (long)SEQ * DIM, nullptr, 1.0f, SEQ);
        gemm128<true, float><<<dim3(DIM / 128, (B_BATCH * SEQ) / 128, 1), blk, 0, stream>>>(
            O, DIM, 0, wpb, DIM, 0, out, DIM, 0, b_prj, 1.0f, DIM);
    } else {
        // minimal-workspace fallback: per-batch pipeline (~29 MB scratch)
        const size_t xE  = (size_t)SEQ * DIM;    // per-batch
        const size_t qE  = (size_t)SEQ * E3;
        const size_t sE1 = (size_t)SEQ * SEQ;
        __hip_bfloat16* wqb = (__hip_bfloat16*)d_ws;
        __hip_bfloat16* wpb = wqb + WQE;
        __hip_bfloat16* xb  = wpb + WPE;
        __hip_bfloat16* qkv = xb + xE;
        __hip_bfloat16* S   = qkv + qE;
        __hip_bfloat16* O   = S + sE1;

        cvt_f32_bf16<<<dim3((WQE / 8 + 255) / 256), blk, 0, stream>>>(w_qkv, wqb, WQE / 8);
        cvt_f32_bf16<<<dim3((WPE / 8 + 255) / 256), blk, 0, stream>>>(w_prj, wpb, WPE / 8);

        for (int b = 0; b < B_BATCH; ++b) {
            const float* xf = x + (size_t)b * xE;
            cvt_f32_bf16<<<dim3((xE / 8 + 255) / 256), blk, 0, stream>>>(xf, xb, xE / 8);
            gemm128<true, __hip_bfloat16><<<dim3(E3 / 128, SEQ / 128, 1), blk, 0, stream>>>(
                xb, DIM, 0, wqb, DIM, 0, qkv, E3, 0, b_qkv, 1.0f, DIM);
            gemm128<true, __hip_bfloat16><<<dim3(SEQ / 128, SEQ / 128, 1), blk, 0, stream>>>(
                qkv, E3, 0, qkv + DIM, E3, 0, S, SEQ, 0, nullptr, alpha, DIM);
            softmax_rows<<<dim3(SEQ, 1, 1), blk, 0, stream>>>(S, 0);
            gemm128<false, __hip_bfloat16><<<dim3(DIM / 128, SEQ / 128, 1), blk, 0, stream>>>(
                S, SEQ, 0, qkv + 2 * DIM, E3, 0, O, DIM, 0, nullptr, 1.0f, SEQ);
            gemm128<true, float><<<dim3(DIM / 128, SEQ / 128, 1), blk, 0, stream>>>(
                O, DIM, 0, wpb, DIM, 0, out + (size_t)b * xE, DIM, 0, b_prj, 1.0f, DIM);
        }
    }
}

// Round 4
// 395.767 us; speedup vs baseline: 1.4089x; 1.4089x over previous
//
#include <hip/hip_runtime.h>
#include <hip/hip_bf16.h>
#include <math.h>

#define B_BATCH 8
#define SEQ 2048
#define DIM 768
#define E3 2304   // 3*DIM

typedef __bf16 bf16x8 __attribute__((ext_vector_type(8)));
typedef float floatx4 __attribute__((ext_vector_type(4)));

__device__ __forceinline__ void load_lds_16B(const __hip_bfloat16* g, __hip_bfloat16* l) {
    __builtin_amdgcn_global_load_lds((const __attribute__((address_space(1))) void*)g,
                                     (__attribute__((address_space(3))) void*)l, 16, 0, 0);
}

template<typename T> __device__ __forceinline__ T to_out(float v);
template<> __device__ __forceinline__ float to_out<float>(float v) { return v; }
template<> __device__ __forceinline__ __hip_bfloat16 to_out<__hip_bfloat16>(float v) { return __float2bfloat16(v); }

// fp32 -> bf16 conversion, 8 elements per thread
__global__ __launch_bounds__(256, 4)
void cvt_f32_bf16(const float* __restrict__ in, __hip_bfloat16* __restrict__ out, long n8)
{
    const long i = (long)blockIdx.x * blockDim.x + threadIdx.x;
    if (i >= n8) return;
    const float4* p = (const float4*)in + i * 2;
    const float4 a = p[0], b = p[1];
    union { uint4 u; __hip_bfloat16 h[8]; } t;
    t.h[0] = __float2bfloat16(a.x); t.h[1] = __float2bfloat16(a.y);
    t.h[2] = __float2bfloat16(a.z); t.h[3] = __float2bfloat16(a.w);
    t.h[4] = __float2bfloat16(b.x); t.h[5] = __float2bfloat16(b.y);
    t.h[6] = __float2bfloat16(b.z); t.h[7] = __float2bfloat16(b.w);
    ((uint4*)out)[i] = t.u;
}

// 64x64 LDS-tiled transpose: out[c][r] = in[r][c].  grid (rows/64, cols/64, Z)
__global__ __launch_bounds__(256, 4)
void transpose64(const __hip_bfloat16* __restrict__ in, long ldi, long si,
                 __hip_bfloat16* __restrict__ out, long ldo, long so)
{
    __shared__ __hip_bfloat16 t[64][65];   // +1 pad
    in  += (long)blockIdx.z * si;
    out += (long)blockIdx.z * so;
    const int r0 = blockIdx.x * 64;   // row base in `in`
    const int c0 = blockIdx.y * 64;   // col base in `in`
    const int tid = threadIdx.x;
    const int r  = tid >> 3;          // 0..31
    const int c8 = (tid & 7) * 8;
#pragma unroll
    for (int h = 0; h < 2; ++h) {
        const int row = r + h * 32;
        union { uint4 u; __hip_bfloat16 v[8]; } tmp;
        tmp.u = *(const uint4*)(in + (long)(r0 + row) * ldi + c0 + c8);
#pragma unroll
        for (int j = 0; j < 8; ++j) t[row][c8 + j] = tmp.v[j];
    }
    __syncthreads();
#pragma unroll
    for (int h = 0; h < 2; ++h) {
        const int cr = r + h * 32;    // output row = input col
        union { uint4 u; __hip_bfloat16 v[8]; } tmp;
#pragma unroll
        for (int j = 0; j < 8; ++j) tmp.v[j] = t[c8 + j][cr];
        *(uint4*)(out + (long)(c0 + cr) * ldo + r0 + c8) = tmp.u;
    }
}

// C[M x N] = scale * (A [M x K] * B^T) + bias, B is [N x K] row-major.
// 1D grid = MB*NB*ZB. XCD swizzle (correctness-critical decode — audited):
//   pairs = MB*ZB (must be %8==0, true for every launch below)
//   id = xcd + 8*(q*NB + nblk);  pair = xcd*(pairs/8) + q
// => bijection onto (zblk, mblk, nblk); all NB n-blocks of one (z,m) pair
//    share id%8, i.e. land on one XCD under round-robin dispatch.
template<typename OutT>
__global__ __launch_bounds__(256, 2)
void gemm128(const __hip_bfloat16* __restrict__ A, long lda, long sA,
             const __hip_bfloat16* __restrict__ Bm, long ldb, long sB,
             OutT* __restrict__ C, long ldc, long sC,
             const float* __restrict__ bias, float scale, int K,
             int MB, int NB)
{
    __shared__ __hip_bfloat16 As[128 * 32];
    __shared__ __hip_bfloat16 Bs[128 * 32];

    const int id    = blockIdx.x;
    const int xcd   = id & 7;
    const int jj    = id >> 3;
    const int pairs = gridDim.x / NB;      // MB*ZB
    const int ppx   = pairs >> 3;
    const int pair  = xcd * ppx + jj / NB;
    const int nblk  = jj % NB;
    const int zblk  = pair / MB;
    const int mblk  = pair % MB;

    A  += (long)zblk * sA;
    Bm += (long)zblk * sB;
    C  += (long)zblk * sC;

    const int n0   = nblk * 128;
    const int m0   = mblk * 128;
    const int tid  = threadIdx.x;
    const int wave = tid >> 6;
    const int lane = tid & 63;
    const int wm   = (wave & 1) * 64;
    const int wn   = (wave >> 1) * 64;

    // global_load_lds: HW writes LDS at (uniform base) + lane*16B.
    const int sr = lane >> 2;
    const int sc = (lane & 3) * 8;

    // MFMA A/B fragment: m(or n)=lane&15, k=(lane>>4)*8 + j  [verified m89/m91]
    const int fr = lane & 15;
    const int fk = (lane >> 4) * 8;

    floatx4 acc[4][4] = {};

    for (int k0 = 0; k0 < K; k0 += 32) {
#pragma unroll
        for (int c = 0; c < 2; ++c) {
            const int chunk = wave * 2 + c;            // wave-uniform
            const int row   = chunk * 16 + sr;
            load_lds_16B(A  + (long)(m0 + row) * lda + (k0 + sc), As + chunk * 512);
            load_lds_16B(Bm + (long)(n0 + row) * ldb + (k0 + sc), Bs + chunk * 512);
        }
        __syncthreads();

        bf16x8 af[4], bfr[4];
#pragma unroll
        for (int i = 0; i < 4; ++i) {
            af[i]  = *(const bf16x8*)(As + (wm + i * 16 + fr) * 32 + fk);
            bfr[i] = *(const bf16x8*)(Bs + (wn + i * 16 + fr) * 32 + fk);
        }
#pragma unroll
        for (int mi = 0; mi < 4; ++mi)
#pragma unroll
            for (int ni = 0; ni < 4; ++ni)
                acc[mi][ni] = __builtin_amdgcn_mfma_f32_16x16x32_bf16(
                    af[mi], bfr[ni], acc[mi][ni], 0, 0, 0);
        __syncthreads();
    }

    // C/D layout: col = lane&15, row = (lane>>4)*4 + reg  [verified m89/m91]
    const int cr = (lane >> 4) * 4;
    const int cc = lane & 15;
#pragma unroll
    for (int ni = 0; ni < 4; ++ni) {
        const int col = n0 + wn + ni * 16 + cc;
        const float bv = bias ? bias[col] : 0.0f;
#pragma unroll
        for (int mi = 0; mi < 4; ++mi) {
#pragma unroll
            for (int r = 0; r < 4; ++r) {
                const int row = m0 + wm + mi * 16 + cr + r;
                C[(long)row * ldc + col] = to_out<OutT>(acc[mi][ni][r] * scale + bv);
            }
        }
    }
}

// in-place softmax over rows of length SEQ (bf16), one block per row
__global__ __launch_bounds__(256, 4)
void softmax_rows(__hip_bfloat16* __restrict__ S, long sB)
{
    __hip_bfloat16* row = S + (long)blockIdx.z * sB + (long)blockIdx.x * SEQ;
    const int tid  = threadIdx.x;
    const int wave = tid >> 6;
    const int lane = tid & 63;

    union { uint4 u; __hip_bfloat16 h[8]; } t;
    t.u = *(const uint4*)(row + tid * 8);
    float v[8];
#pragma unroll
    for (int j = 0; j < 8; ++j) v[j] = __bfloat162float(t.h[j]);

    float mx = v[0];
#pragma unroll
    for (int j = 1; j < 8; ++j) mx = fmaxf(mx, v[j]);
    for (int off = 32; off > 0; off >>= 1) mx = fmaxf(mx, __shfl_xor(mx, off, 64));

    __shared__ float redm[4], reds[4];
    if (lane == 0) redm[wave] = mx;
    __syncthreads();
    mx = fmaxf(fmaxf(redm[0], redm[1]), fmaxf(redm[2], redm[3]));

    float e[8], s = 0.f;
#pragma unroll
    for (int j = 0; j < 8; ++j) { e[j] = __expf(v[j] - mx); s += e[j]; }
    for (int off = 32; off > 0; off >>= 1) s += __shfl_xor(s, off, 64);
    if (lane == 0) reds[wave] = s;
    __syncthreads();
    s = reds[0] + reds[1] + reds[2] + reds[3];
    const float inv = 1.f / s;

#pragma unroll
    for (int j = 0; j < 8; ++j) t.h[j] = __float2bfloat16(e[j] * inv);
    *(uint4*)(row + tid * 8) = t.u;
}

extern "C" void kernel_launch(void* const* d_in, const int* in_sizes, int n_in,
                              void* d_out, int out_size, void* d_ws, size_t ws_size,
                              hipStream_t stream)
{
    const float* x     = (const float*)d_in[0];
    const float* w_qkv = (const float*)d_in[1];
    const float* b_qkv = (const float*)d_in[2];
    const float* w_prj = (const float*)d_in[3];
    const float* b_prj = (const float*)d_in[4];
    float* out = (float*)d_out;

    const float alpha = 1.0f / (sqrtf((float)DIM) * 3.0f);  // qk scale / temperature

    const size_t XE   = (size_t)B_BATCH * SEQ * DIM;   // 12.58M (also Vt size)
    const size_t WQE  = (size_t)E3 * DIM;
    const size_t WPE  = (size_t)DIM * DIM;
    const size_t QKVE = (size_t)B_BATCH * SEQ * E3;
    const size_t SE   = (size_t)B_BATCH * SEQ * SEQ;
    const size_t OE   = XE;
    dim3 blk(256);

    const size_t full_bytes = (XE + WQE + WPE + QKVE + SE + OE) * sizeof(__hip_bfloat16);

    if (ws_size >= full_bytes) {
        __hip_bfloat16* xb  = (__hip_bfloat16*)d_ws;   // x-bf16, then reused as Vt
        __hip_bfloat16* wqb = xb + XE;
        __hip_bfloat16* wpb = wqb + WQE;
        __hip_bfloat16* qkv = wpb + WPE;
        __hip_bfloat16* S   = qkv + QKVE;
        __hip_bfloat16* O   = S + SE;
        __hip_bfloat16* Vt  = xb;                      // xb dead after QKV GEMM

        cvt_f32_bf16<<<dim3((XE / 8 + 255) / 256), blk, 0, stream>>>(x, xb, XE / 8);
        cvt_f32_bf16<<<dim3((WQE / 8 + 255) / 256), blk, 0, stream>>>(w_qkv, wqb, WQE / 8);
        cvt_f32_bf16<<<dim3((WPE / 8 + 255) / 256), blk, 0, stream>>>(w_prj, wpb, WPE / 8);

        // qkv = x @ w_qkv^T + b   [16384 x 2304]   pairs=128
        gemm128<__hip_bfloat16><<<dim3(128 * 18), blk, 0, stream>>>(
            xb, DIM, 0, wqb, DIM, 0, qkv, E3, 0, b_qkv, 1.0f, DIM, 128, 18);
        // Vt[b] = V[b]^T  [768 x 2048] per batch
        transpose64<<<dim3(SEQ / 64, DIM / 64, B_BATCH), blk, 0, stream>>>(
            qkv + 2 * DIM, E3, (long)SEQ * E3, Vt, SEQ, (long)DIM * SEQ);
        // S = alpha * Q @ K^T   [8][2048 x 2048]   pairs=128
        gemm128<__hip_bfloat16><<<dim3(16 * 16 * B_BATCH), blk, 0, stream>>>(
            qkv, E3, (long)SEQ * E3, qkv + DIM, E3, (long)SEQ * E3,
            S, SEQ, (long)SEQ * SEQ, nullptr, alpha, DIM, 16, 16);
        softmax_rows<<<dim3(SEQ, 1, B_BATCH), blk, 0, stream>>>(S, (long)SEQ * SEQ);
        // O = P @ Vt^T   [8][2048 x 768]   pairs=128
        gemm128<__hip_bfloat16><<<dim3(16 * 6 * B_BATCH), blk, 0, stream>>>(
            S, SEQ, (long)SEQ * SEQ, Vt, SEQ, (long)DIM * SEQ,
            O, DIM, (long)SEQ * DIM, nullptr, 1.0f, SEQ, 16, 6);
        // out = O @ w_proj^T + b  [16384 x 768] fp32   pairs=128
        gemm128<float><<<dim3(128 * 6), blk, 0, stream>>>(
            O, DIM, 0, wpb, DIM, 0, out, DIM, 0, b_prj, 1.0f, DIM, 128, 6);
    } else {
        // minimal-workspace fallback: per-batch pipeline (~30 MB scratch)
        const size_t xE  = (size_t)SEQ * DIM;
        const size_t qE  = (size_t)SEQ * E3;
        const size_t sE1 = (size_t)SEQ * SEQ;
        __hip_bfloat16* wqb = (__hip_bfloat16*)d_ws;
        __hip_bfloat16* wpb = wqb + WQE;
        __hip_bfloat16* xb  = wpb + WPE;            // reused as Vt per batch
        __hip_bfloat16* qkv = xb + xE;
        __hip_bfloat16* S   = qkv + qE;
        __hip_bfloat16* O   = S + sE1;
        __hip_bfloat16* Vt  = xb;

        cvt_f32_bf16<<<dim3((WQE / 8 + 255) / 256), blk, 0, stream>>>(w_qkv, wqb, WQE / 8);
        cvt_f32_bf16<<<dim3((WPE / 8 + 255) / 256), blk, 0, stream>>>(w_prj, wpb, WPE / 8);

        for (int b = 0; b < B_BATCH; ++b) {
            const float* xf = x + (size_t)b * xE;
            cvt_f32_bf16<<<dim3((xE / 8 + 255) / 256), blk, 0, stream>>>(xf, xb, xE / 8);
            gemm128<__hip_bfloat16><<<dim3(16 * 18), blk, 0, stream>>>(
                xb, DIM, 0, wqb, DIM, 0, qkv, E3, 0, b_qkv, 1.0f, DIM, 16, 18);
            transpose64<<<dim3(SEQ / 64, DIM / 64, 1), blk, 0, stream>>>(
                qkv + 2 * DIM, E3, 0, Vt, SEQ, 0);
            gemm128<__hip_bfloat16><<<dim3(16 * 16), blk, 0, stream>>>(
                qkv, E3, 0, qkv + DIM, E3, 0, S, SEQ, 0, nullptr, alpha, DIM, 16, 16);
            softmax_rows<<<dim3(SEQ, 1, 1), blk, 0, stream>>>(S, 0);
            gemm128<__hip_bfloat16><<<dim3(16 * 6), blk, 0, stream>>>(
                S, SEQ, 0, Vt, SEQ, 0, O, DIM, 0, nullptr, 1.0f, SEQ, 16, 6);
            gemm128<float><<<dim3(16 * 6), blk, 0, stream>>>(
                O, DIM, 0, wpb, DIM, 0, out + (size_t)b * xE, DIM, 0, b_prj, 1.0f, DIM, 16, 6);
        }
    }
}

// Round 5
// 373.118 us; speedup vs baseline: 1.4944x; 1.0607x over previous
//
#include <hip/hip_runtime.h>
#include <hip/hip_bf16.h>
#include <math.h>

#define B_BATCH 8
#define SEQ 2048
#define DIM 768
#define E3 2304   // 3*DIM

typedef __bf16 bf16x8 __attribute__((ext_vector_type(8)));
typedef float floatx4 __attribute__((ext_vector_type(4)));

__device__ __forceinline__ void load_lds_16B(const __hip_bfloat16* g, __hip_bfloat16* l) {
    __builtin_amdgcn_global_load_lds((const __attribute__((address_space(1))) void*)g,
                                     (__attribute__((address_space(3))) void*)l, 16, 0, 0);
}

template<typename T> __device__ __forceinline__ T to_out(float v);
template<> __device__ __forceinline__ float to_out<float>(float v) { return v; }
template<> __device__ __forceinline__ __hip_bfloat16 to_out<__hip_bfloat16>(float v) { return __float2bfloat16(v); }

// fp32 -> bf16 conversion, 8 elements per thread
__global__ __launch_bounds__(256, 4)
void cvt_f32_bf16(const float* __restrict__ in, __hip_bfloat16* __restrict__ out, long n8)
{
    const long i = (long)blockIdx.x * blockDim.x + threadIdx.x;
    if (i >= n8) return;
    const float4* p = (const float4*)in + i * 2;
    const float4 a = p[0], b = p[1];
    union { uint4 u; __hip_bfloat16 h[8]; } t;
    t.h[0] = __float2bfloat16(a.x); t.h[1] = __float2bfloat16(a.y);
    t.h[2] = __float2bfloat16(a.z); t.h[3] = __float2bfloat16(a.w);
    t.h[4] = __float2bfloat16(b.x); t.h[5] = __float2bfloat16(b.y);
    t.h[6] = __float2bfloat16(b.z); t.h[7] = __float2bfloat16(b.w);
    ((uint4*)out)[i] = t.u;
}

// 64x64 LDS-tiled transpose: out[c][r] = in[r][c].  grid (rows/64, cols/64, Z)
__global__ __launch_bounds__(256, 4)
void transpose64(const __hip_bfloat16* __restrict__ in, long ldi, long si,
                 __hip_bfloat16* __restrict__ out, long ldo, long so)
{
    __shared__ __hip_bfloat16 t[64][65];   // +1 pad
    in  += (long)blockIdx.z * si;
    out += (long)blockIdx.z * so;
    const int r0 = blockIdx.x * 64;   // row base in `in`
    const int c0 = blockIdx.y * 64;   // col base in `in`
    const int tid = threadIdx.x;
    const int r  = tid >> 3;          // 0..31
    const int c8 = (tid & 7) * 8;
#pragma unroll
    for (int h = 0; h < 2; ++h) {
        const int row = r + h * 32;
        union { uint4 u; __hip_bfloat16 v[8]; } tmp;
        tmp.u = *(const uint4*)(in + (long)(r0 + row) * ldi + c0 + c8);
#pragma unroll
        for (int j = 0; j < 8; ++j) t[row][c8 + j] = tmp.v[j];
    }
    __syncthreads();
#pragma unroll
    for (int h = 0; h < 2; ++h) {
        const int cr = r + h * 32;    // output row = input col
        union { uint4 u; __hip_bfloat16 v[8]; } tmp;
#pragma unroll
        for (int j = 0; j < 8; ++j) tmp.v[j] = t[c8 + j][cr];
        *(uint4*)(out + (long)(c0 + cr) * ldo + r0 + c8) = tmp.u;
    }
}

// C[M x N] = f( A [M x K] * B^T ), B is [N x K] row-major.
// EPI = 0: C = scale*AB^T + bias         (standard GEMM)
// EPI = 1: C = exp(scale*AB^T)           (scores -> unnormalized softmax numerator;
//          safe without max-subtraction: |scale*s| < ~1 for this problem)
// EPI = 2: C = (AB^T) / rowsum(A)        (PV with fused softmax denominator;
//          A = E matrix, row sums accumulated from the A-fragments in-loop)
// 1D grid = MB*NB*ZB. XCD swizzle (correctness-critical decode — audited r3):
//   pairs = MB*ZB (must be %8==0 — true for every launch below)
//   id = xcd + 8*(q*NB + nblk);  pair = xcd*(pairs/8) + q  => bijection.
template<typename OutT, int EPI>
__global__ __launch_bounds__(256, 2)
void gemm128(const __hip_bfloat16* __restrict__ A, long lda, long sA,
             const __hip_bfloat16* __restrict__ Bm, long ldb, long sB,
             OutT* __restrict__ C, long ldc, long sC,
             const float* __restrict__ bias, float scale, int K,
             int MB, int NB)
{
    __shared__ __hip_bfloat16 As[128 * 32];
    __shared__ __hip_bfloat16 Bs[128 * 32];
    __shared__ float lsum[128];            // EPI==2 row-sum exchange

    const int id    = blockIdx.x;
    const int xcd   = id & 7;
    const int jj    = id >> 3;
    const int pairs = gridDim.x / NB;      // MB*ZB
    const int ppx   = pairs >> 3;
    const int pair  = xcd * ppx + jj / NB;
    const int nblk  = jj % NB;
    const int zblk  = pair / MB;
    const int mblk  = pair % MB;

    A  += (long)zblk * sA;
    Bm += (long)zblk * sB;
    C  += (long)zblk * sC;

    const int n0   = nblk * 128;
    const int m0   = mblk * 128;
    const int tid  = threadIdx.x;
    const int wave = tid >> 6;
    const int lane = tid & 63;
    const int wm   = (wave & 1) * 64;
    const int wn   = (wave >> 1) * 64;

    // global_load_lds: HW writes LDS at (uniform base) + lane*16B.
    const int sr = lane >> 2;
    const int sc = (lane & 3) * 8;

    // MFMA A/B fragment: m(or n)=lane&15, k=(lane>>4)*8 + j  [verified m89/m91]
    const int fr = lane & 15;
    const int fk = (lane >> 4) * 8;

    floatx4 acc[4][4] = {};
    float rsum[4] = {0.f, 0.f, 0.f, 0.f};  // EPI==2: per-mi partial row sums

    for (int k0 = 0; k0 < K; k0 += 32) {
#pragma unroll
        for (int c = 0; c < 2; ++c) {
            const int chunk = wave * 2 + c;            // wave-uniform
            const int row   = chunk * 16 + sr;
            load_lds_16B(A  + (long)(m0 + row) * lda + (k0 + sc), As + chunk * 512);
            load_lds_16B(Bm + (long)(n0 + row) * ldb + (k0 + sc), Bs + chunk * 512);
        }
        __syncthreads();

        bf16x8 af[4], bfr[4];
#pragma unroll
        for (int i = 0; i < 4; ++i) {
            af[i]  = *(const bf16x8*)(As + (wm + i * 16 + fr) * 32 + fk);
            bfr[i] = *(const bf16x8*)(Bs + (wn + i * 16 + fr) * 32 + fk);
        }
        if constexpr (EPI == 2) {
#pragma unroll
            for (int mi = 0; mi < 4; ++mi)
#pragma unroll
                for (int j = 0; j < 8; ++j)
                    rsum[mi] += (float)af[mi][j];
        }
#pragma unroll
        for (int mi = 0; mi < 4; ++mi)
#pragma unroll
            for (int ni = 0; ni < 4; ++ni)
                acc[mi][ni] = __builtin_amdgcn_mfma_f32_16x16x32_bf16(
                    af[mi], bfr[ni], acc[mi][ni], 0, 0, 0);
        __syncthreads();
    }

    if constexpr (EPI == 2) {
        // lanes sharing (lane&15) = same row; reduce across the 4 k-quads
#pragma unroll
        for (int mi = 0; mi < 4; ++mi) {
            rsum[mi] += __shfl_xor(rsum[mi], 16, 64);
            rsum[mi] += __shfl_xor(rsum[mi], 32, 64);
        }
        if (wave < 2 && (lane >> 4) == 0) {   // waves 0,1 cover rows 0-63 / 64-127
#pragma unroll
            for (int mi = 0; mi < 4; ++mi)
                lsum[wm + mi * 16 + (lane & 15)] = rsum[mi];
        }
        __syncthreads();
    }

    // C/D layout: col = lane&15, row = (lane>>4)*4 + reg  [verified m89/m91]
    const int cr = (lane >> 4) * 4;
    const int cc = lane & 15;

    float inv[4][4];
    if constexpr (EPI == 2) {
#pragma unroll
        for (int mi = 0; mi < 4; ++mi)
#pragma unroll
            for (int r = 0; r < 4; ++r)
                inv[mi][r] = 1.0f / lsum[wm + mi * 16 + cr + r];
    }

#pragma unroll
    for (int ni = 0; ni < 4; ++ni) {
        const int col = n0 + wn + ni * 16 + cc;
        const float bv = (EPI == 0 && bias) ? bias[col] : 0.0f;
#pragma unroll
        for (int mi = 0; mi < 4; ++mi) {
#pragma unroll
            for (int r = 0; r < 4; ++r) {
                const int row = m0 + wm + mi * 16 + cr + r;
                float v = acc[mi][ni][r];
                if constexpr (EPI == 0)      v = v * scale + bv;
                else if constexpr (EPI == 1) v = __expf(v * scale);
                else                         v = v * inv[mi][r];
                C[(long)row * ldc + col] = to_out<OutT>(v);
            }
        }
    }
}

extern "C" void kernel_launch(void* const* d_in, const int* in_sizes, int n_in,
                              void* d_out, int out_size, void* d_ws, size_t ws_size,
                              hipStream_t stream)
{
    const float* x     = (const float*)d_in[0];
    const float* w_qkv = (const float*)d_in[1];
    const float* b_qkv = (const float*)d_in[2];
    const float* w_prj = (const float*)d_in[3];
    const float* b_prj = (const float*)d_in[4];
    float* out = (float*)d_out;

    const float alpha = 1.0f / (sqrtf((float)DIM) * 3.0f);  // qk scale / temperature

    const size_t XE   = (size_t)B_BATCH * SEQ * DIM;   // 12.58M (also Vt size)
    const size_t WQE  = (size_t)E3 * DIM;
    const size_t WPE  = (size_t)DIM * DIM;
    const size_t QKVE = (size_t)B_BATCH * SEQ * E3;
    const size_t SE   = (size_t)B_BATCH * SEQ * SEQ;
    const size_t OE   = XE;
    dim3 blk(256);

    const size_t full_bytes = (XE + WQE + WPE + QKVE + SE + OE) * sizeof(__hip_bfloat16);

    if (ws_size >= full_bytes) {
        __hip_bfloat16* xb  = (__hip_bfloat16*)d_ws;   // x-bf16, then reused as Vt
        __hip_bfloat16* wqb = xb + XE;
        __hip_bfloat16* wpb = wqb + WQE;
        __hip_bfloat16* qkv = wpb + WPE;
        __hip_bfloat16* S   = qkv + QKVE;              // holds E = exp(alpha*QK^T)
        __hip_bfloat16* O   = S + SE;
        __hip_bfloat16* Vt  = xb;                      // xb dead after QKV GEMM

        cvt_f32_bf16<<<dim3((XE / 8 + 255) / 256), blk, 0, stream>>>(x, xb, XE / 8);
        cvt_f32_bf16<<<dim3((WQE / 8 + 255) / 256), blk, 0, stream>>>(w_qkv, wqb, WQE / 8);
        cvt_f32_bf16<<<dim3((WPE / 8 + 255) / 256), blk, 0, stream>>>(w_prj, wpb, WPE / 8);

        // qkv = x @ w_qkv^T + b   [16384 x 2304]   pairs=128
        gemm128<__hip_bfloat16, 0><<<dim3(128 * 18), blk, 0, stream>>>(
            xb, DIM, 0, wqb, DIM, 0, qkv, E3, 0, b_qkv, 1.0f, DIM, 128, 18);
        // Vt[b] = V[b]^T  [768 x 2048] per batch
        transpose64<<<dim3(SEQ / 64, DIM / 64, B_BATCH), blk, 0, stream>>>(
            qkv + 2 * DIM, E3, (long)SEQ * E3, Vt, SEQ, (long)DIM * SEQ);
        // E = exp(alpha * Q @ K^T)   [8][2048 x 2048]   pairs=128
        gemm128<__hip_bfloat16, 1><<<dim3(16 * 16 * B_BATCH), blk, 0, stream>>>(
            qkv, E3, (long)SEQ * E3, qkv + DIM, E3, (long)SEQ * E3,
            S, SEQ, (long)SEQ * SEQ, nullptr, alpha, DIM, 16, 16);
        // O = (E @ Vt^T) / rowsum(E)   [8][2048 x 768]   pairs=128
        gemm128<__hip_bfloat16, 2><<<dim3(16 * 6 * B_BATCH), blk, 0, stream>>>(
            S, SEQ, (long)SEQ * SEQ, Vt, SEQ, (long)DIM * SEQ,
            O, DIM, (long)SEQ * DIM, nullptr, 1.0f, SEQ, 16, 6);
        // out = O @ w_proj^T + b  [16384 x 768] fp32   pairs=128
        gemm128<float, 0><<<dim3(128 * 6), blk, 0, stream>>>(
            O, DIM, 0, wpb, DIM, 0, out, DIM, 0, b_prj, 1.0f, DIM, 128, 6);
    } else {
        // minimal-workspace fallback: per-batch pipeline (~30 MB scratch)
        const size_t xE  = (size_t)SEQ * DIM;
        const size_t qE  = (size_t)SEQ * E3;
        const size_t sE1 = (size_t)SEQ * SEQ;
        __hip_bfloat16* wqb = (__hip_bfloat16*)d_ws;
        __hip_bfloat16* wpb = wqb + WQE;
        __hip_bfloat16* xb  = wpb + WPE;            // reused as Vt per batch
        __hip_bfloat16* qkv = xb + xE;
        __hip_bfloat16* S   = qkv + qE;
        __hip_bfloat16* O   = S + sE1;
        __hip_bfloat16* Vt  = xb;

        cvt_f32_bf16<<<dim3((WQE / 8 + 255) / 256), blk, 0, stream>>>(w_qkv, wqb, WQE / 8);
        cvt_f32_bf16<<<dim3((WPE / 8 + 255) / 256), blk, 0, stream>>>(w_prj, wpb, WPE / 8);

        for (int b = 0; b < B_BATCH; ++b) {
            const float* xf = x + (size_t)b * xE;
            cvt_f32_bf16<<<dim3((xE / 8 + 255) / 256), blk, 0, stream>>>(xf, xb, xE / 8);
            gemm128<__hip_bfloat16, 0><<<dim3(16 * 18), blk, 0, stream>>>(
                xb, DIM, 0, wqb, DIM, 0, qkv, E3, 0, b_qkv, 1.0f, DIM, 16, 18);
            transpose64<<<dim3(SEQ / 64, DIM / 64, 1), blk, 0, stream>>>(
                qkv + 2 * DIM, E3, 0, Vt, SEQ, 0);
            gemm128<__hip_bfloat16, 1><<<dim3(16 * 16), blk, 0, stream>>>(
                qkv, E3, 0, qkv + DIM, E3, 0, S, SEQ, 0, nullptr, alpha, DIM, 16, 16);
            gemm128<__hip_bfloat16, 2><<<dim3(16 * 6), blk, 0, stream>>>(
                S, SEQ, 0, Vt, SEQ, 0, O, DIM, 0, nullptr, 1.0f, SEQ, 16, 6);
            gemm128<float, 0><<<dim3(16 * 6), blk, 0, stream>>>(
                O, DIM, 0, wpb, DIM, 0, out + (size_t)b * xE, DIM, 0, b_prj, 1.0f, DIM, 16, 6);
        }
    }
}